// Round 1
// baseline (81.641 us; speedup 1.0000x reference)
//
#include <hip/hip_runtime.h>
#include <math.h>

// DecoderGATLayer — algebraically simplified.
// S=192, B=2, E=512, H=2, D=256, BH=4. All f32.
// Dead code in reference: exw/we deleted => ex_entity, ex_relation, Wxe, Wxr unused.
// score[bh,t,s] = A[s&3][i] + B[t&3][s] + C[s&3][i] - C[s&3][j] + ba
//   with i = bh*48 + (t>>2), j = (t&3)*48 + (s>>2)
// A[p][r] = Wa[0:256) . qe_s[p][r][:]   (qe_s[2b+h] = h? e : q)
// B[p][s] = Wa[256:512) . ke_s[p][s][:] (ke_s[2b+h] = h? e : k)
// C[m][i] = Wa[512:768) . entity[i][m>>1][(m&1)*256 : +256]

#define SS 192
#define NROW 384      // S*B
// workspace float offsets
#define QO 0
#define KO 98304
#define VO 196608
#define EO 294912
#define TO 393216     // 12*192 = 2304 floats
#define OO 395520     // out_buf [4][192][256]

__global__ __launch_bounds__(256) void k_proj(
    const float* __restrict__ query, const float* __restrict__ entity,
    const float* __restrict__ Wq, const float* __restrict__ bq,
    const float* __restrict__ Wk, const float* __restrict__ bk,
    const float* __restrict__ Wv, const float* __restrict__ bv,
    const float* __restrict__ We, const float* __restrict__ be,
    float* __restrict__ ws)
{
    const int ROWS = 8;
    int bi = blockIdx.x;          // 0..191  (4 mats x 48 row-groups)
    int m  = bi / 48;
    int g  = bi % 48;
    int r0 = g * ROWS;            // r = s*2+b
    const float* src; const float* W; const float* bias; float* dst;
    if      (m == 0) { src = query;  W = Wq; bias = bq; dst = ws + QO; }
    else if (m == 1) { src = query;  W = Wk; bias = bk; dst = ws + KO; }
    else if (m == 2) { src = query;  W = Wv; bias = bv; dst = ws + VO; }
    else             { src = entity; W = We; bias = be; dst = ws + EO; }

    int d = threadIdx.x;          // output column 0..255
    float acc[ROWS];
    #pragma unroll
    for (int r = 0; r < ROWS; r++) acc[r] = 0.f;

    const float4* W4 = (const float4*)(W + d * 512);
    for (int e4 = 0; e4 < 128; e4++) {
        float4 w = W4[e4];
        #pragma unroll
        for (int r = 0; r < ROWS; r++) {
            float4 a = ((const float4*)(src + (size_t)(r0 + r) * 512))[e4];  // wave-uniform -> s_load
            acc[r] += w.x * a.x + w.y * a.y + w.z * a.z + w.w * a.w;
        }
    }
    float bd = bias[d];
    #pragma unroll
    for (int r = 0; r < ROWS; r++)
        dst[(size_t)(r0 + r) * 256 + d] = acc[r] + bd;
}

__global__ __launch_bounds__(256) void k_tabs(
    const float* __restrict__ entity, const float* __restrict__ Wa,
    float* __restrict__ ws)
{
    int w    = blockIdx.x * 4 + (threadIdx.x >> 6);  // 0..2303 (12 tabs x 192)
    int lane = threadIdx.x & 63;
    int tab  = w / SS;
    int idx  = w % SS;
    const float* q = ws + QO;
    const float* k = ws + KO;
    const float* e = ws + EO;
    const float* src; const float* wt;
    if (tab < 4) {
        int b = tab >> 1, h = tab & 1;
        src = (h ? e : q) + (size_t)(idx * 2 + b) * 256;  wt = Wa;
    } else if (tab < 8) {
        int p = tab - 4; int b = p >> 1, h = p & 1;
        src = (h ? e : k) + (size_t)(idx * 2 + b) * 256;  wt = Wa + 256;
    } else {
        int m = tab - 8;
        src = entity + (size_t)(idx * 2 + (m >> 1)) * 512 + (m & 1) * 256;  wt = Wa + 512;
    }
    float p = 0.f;
    #pragma unroll
    for (int i = 0; i < 4; i++) p += src[lane + 64 * i] * wt[lane + 64 * i];
    #pragma unroll
    for (int off = 32; off >= 1; off >>= 1) p += __shfl_xor(p, off, 64);
    if (lane == 0) ws[TO + tab * SS + idx] = p;
}

__global__ __launch_bounds__(256) void k_attn(
    const float* __restrict__ ba_p, float* __restrict__ ws)
{
    __shared__ float sp[SS];
    __shared__ float red[256];
    int bi = blockIdx.x;       // 0..767
    int bh = bi & 3;
    int t  = bi >> 2;
    int i_idx = bh * 48 + (t >> 2);
    int tmod  = t & 3;
    const float* T = ws + TO;
    float ba = ba_p[0];
    int tid = threadIdx.x;

    float x = -1e30f;
    if (tid < SS) {
        int s_ = tid;
        int m  = s_ & 3;
        int j  = tmod * 48 + (s_ >> 2);
        float sc = T[m * SS + i_idx] + T[(4 + tmod) * SS + s_]
                 + T[(8 + m) * SS + i_idx] - T[(8 + m) * SS + j] + ba;
        x = (sc >= 0.f) ? sc : 0.01f * sc;   // leaky_relu(0.01)
    }
    red[tid] = x;
    __syncthreads();
    for (int o = 128; o >= 1; o >>= 1) {
        if (tid < o) red[tid] = fmaxf(red[tid], red[tid + o]);
        __syncthreads();
    }
    float mx = red[0];
    __syncthreads();
    float p = (tid < SS) ? __expf(x - mx) : 0.f;
    if (tid < SS) sp[tid] = p;
    red[tid] = p;
    __syncthreads();
    for (int o = 128; o >= 1; o >>= 1) {
        if (tid < o) red[tid] += red[tid + o];
        __syncthreads();
    }
    float inv = 1.f / red[0];

    // PV: out[bh][t][d] = sum_s aw[s] * ve_s[bh][s][d]
    int b = bh >> 1, h = bh & 1;
    const float* base = (h ? ws + EO : ws + VO) + b * 256 + tid;
    float acc = 0.f;
    #pragma unroll 4
    for (int s = 0; s < SS; s++) acc += sp[s] * base[(size_t)s * 512];
    ws[OO + ((size_t)bh * SS + t) * 256 + tid] = acc * inv;
}

__global__ __launch_bounds__(256) void k_out(
    const float* __restrict__ Wo, const float* __restrict__ bo,
    const float* __restrict__ ws, float* __restrict__ out)
{
    const int ROWS = 4;
    int r0 = blockIdx.x * ROWS;   // 0..383, r = s*2+b
    int d  = threadIdx.x;         // cols d and d+256
    float acc0[ROWS], acc1[ROWS];
    #pragma unroll
    for (int r = 0; r < ROWS; r++) { acc0[r] = 0.f; acc1[r] = 0.f; }
    const float* obuf = ws + OO;
    const float4* W40 = (const float4*)(Wo + (size_t)d * 512);
    const float4* W41 = (const float4*)(Wo + (size_t)(d + 256) * 512);
    for (int e4 = 0; e4 < 128; e4++) {
        float4 w0 = W40[e4];
        float4 w1 = W41[e4];
        #pragma unroll
        for (int r = 0; r < ROWS; r++) {
            int rr = r0 + r;
            int s = rr >> 1, b = rr & 1;
            const float* rowlo = obuf + (size_t)(2 * b) * 49152 + (size_t)s * 256;
            const float* rowhi = obuf + (size_t)(2 * b + 1) * 49152 + (size_t)s * 256;
            float4 a = (e4 < 64) ? ((const float4*)rowlo)[e4]
                                 : ((const float4*)rowhi)[e4 - 64];   // uniform branch
            acc0[r] += w0.x * a.x + w0.y * a.y + w0.z * a.z + w0.w * a.w;
            acc1[r] += w1.x * a.x + w1.y * a.y + w1.z * a.z + w1.w * a.w;
        }
    }
    float b0 = bo[d], b1 = bo[d + 256];
    #pragma unroll
    for (int r = 0; r < ROWS; r++) {
        out[(size_t)(r0 + r) * 512 + d]       = acc0[r] + b0;
        out[(size_t)(r0 + r) * 512 + d + 256] = acc1[r] + b1;
    }
}

extern "C" void kernel_launch(void* const* d_in, const int* in_sizes, int n_in,
                              void* d_out, int out_size, void* d_ws, size_t ws_size,
                              hipStream_t stream) {
    const float* query  = (const float*)d_in[0];
    const float* entity = (const float*)d_in[1];
    // d_in[2] ex_entity, d_in[3] ex_relation: dead (reference deletes `we`)
    const float* Wq = (const float*)d_in[4];  const float* bq = (const float*)d_in[5];
    const float* Wk = (const float*)d_in[6];  const float* bk = (const float*)d_in[7];
    const float* Wv = (const float*)d_in[8];  const float* bv = (const float*)d_in[9];
    const float* We = (const float*)d_in[10]; const float* be = (const float*)d_in[11];
    // d_in[12..15] Wxe/bxe/Wxr/bxr: dead
    const float* Wa = (const float*)d_in[16]; const float* ba = (const float*)d_in[17];
    const float* Wo = (const float*)d_in[18]; const float* bo = (const float*)d_in[19];
    float* ws  = (float*)d_ws;
    float* out = (float*)d_out;

    hipLaunchKernelGGL(k_proj, dim3(192), dim3(256), 0, stream,
                       query, entity, Wq, bq, Wk, bk, Wv, bv, We, be, ws);
    hipLaunchKernelGGL(k_tabs, dim3(576), dim3(256), 0, stream, entity, Wa, ws);
    hipLaunchKernelGGL(k_attn, dim3(768), dim3(256), 0, stream, ba, ws);
    hipLaunchKernelGGL(k_out,  dim3(96),  dim3(256), 0, stream, Wo, bo, ws, out);
}

// Round 3
// 63.352 us; speedup vs baseline: 1.2887x; 1.2887x over previous
//
#include <hip/hip_runtime.h>
#include <math.h>

// DecoderGATLayer — algebraically simplified.
// S=192, B=2, E=512, H=2, D=256, BH=4. All f32.
// Dead inputs: ex_entity, ex_relation, Wxe, Wxr (reference deletes `we`).
// score[bh,t,s] = A[s&3][i] + B[t&3][s] + C[s&3][i] - C[s&3][j] + ba
//   i = bh*48 + (t>>2), j = (t&3)*48 + (s>>2)

#define SS 192
// workspace float offsets
#define QO 0
#define KO 98304
#define VO 196608
#define EO 294912
#define TO 393216     // 12*192 = 2304 floats
#define OO 395520     // attn out, [384][512] row-major (row = 2t+b, col = h*256+d)

#define KC 64
#define LST 34        // LDS k-major stride (even -> float2 aligned; banks (2k+2x)%32 -> <=2-way)

// ---- tiled GEMM core: C[r][d] = sum_k A[r][k] * W[d][k] + bias[d]
// 32x32 output tile, 2x2 per thread, K=512, 256 threads.
__device__ __forceinline__ void gemm_tile(
    const float* __restrict__ A, const float* __restrict__ W,
    const float* __restrict__ bias, float* __restrict__ C, int ldC,
    int r0, int d0, float* __restrict__ AL, float* __restrict__ WL)
{
    int t  = threadIdx.x;
    int td = t & 15;          // d pair index
    int tr = t >> 4;          // r pair index (0..15)
    int lrow = t >> 4;        // staging row (0..15)
    int lf4  = t & 15;        // staging float4 col (0..15)
    float acc00 = 0.f, acc01 = 0.f, acc10 = 0.f, acc11 = 0.f;

    for (int kc = 0; kc < 512; kc += KC) {
        __syncthreads();
        #pragma unroll
        for (int i = 0; i < 2; i++) {
            int x = lrow + 16 * i;                       // 0..31
            float4 av = *(const float4*)(A + (size_t)(r0 + x) * 512 + kc + lf4 * 4);
            float4 wv = *(const float4*)(W + (size_t)(d0 + x) * 512 + kc + lf4 * 4);
            int kb = lf4 * 4;
            AL[(kb + 0) * LST + x] = av.x; AL[(kb + 1) * LST + x] = av.y;
            AL[(kb + 2) * LST + x] = av.z; AL[(kb + 3) * LST + x] = av.w;
            WL[(kb + 0) * LST + x] = wv.x; WL[(kb + 1) * LST + x] = wv.y;
            WL[(kb + 2) * LST + x] = wv.z; WL[(kb + 3) * LST + x] = wv.w;
        }
        __syncthreads();
        #pragma unroll 16
        for (int k = 0; k < KC; k++) {
            float2 w2 = *(const float2*)(WL + k * LST + td * 2);
            float2 a2 = *(const float2*)(AL + k * LST + tr * 2);
            acc00 += a2.x * w2.x; acc01 += a2.x * w2.y;
            acc10 += a2.y * w2.x; acc11 += a2.y * w2.y;
        }
    }
    int d = d0 + td * 2, r = r0 + tr * 2;
    float b0 = bias[d], b1 = bias[d + 1];
    C[(size_t)r * ldC + d]         = acc00 + b0;
    C[(size_t)r * ldC + d + 1]     = acc01 + b1;
    C[(size_t)(r + 1) * ldC + d]     = acc10 + b0;
    C[(size_t)(r + 1) * ldC + d + 1] = acc11 + b1;
}

// 4 projections: grid 4 mats x 12 rtiles x 8 dtiles = 384 blocks
__global__ __launch_bounds__(256) void k_proj(
    const float* __restrict__ query, const float* __restrict__ entity,
    const float* __restrict__ Wq, const float* __restrict__ bq,
    const float* __restrict__ Wk, const float* __restrict__ bk,
    const float* __restrict__ Wv, const float* __restrict__ bv,
    const float* __restrict__ We, const float* __restrict__ be,
    float* __restrict__ ws)
{
    __shared__ float lds[2 * KC * LST];
    int bi = blockIdx.x;
    int m   = bi / 96;
    int rem = bi % 96;
    int d0  = (rem & 7) * 32;
    int r0  = (rem >> 3) * 32;
    const float* src; const float* W; const float* bias; float* dst;
    if      (m == 0) { src = query;  W = Wq; bias = bq; dst = ws + QO; }
    else if (m == 1) { src = query;  W = Wk; bias = bk; dst = ws + KO; }
    else if (m == 2) { src = query;  W = Wv; bias = bv; dst = ws + VO; }
    else             { src = entity; W = We; bias = be; dst = ws + EO; }
    gemm_tile(src, W, bias, dst, 256, r0, d0, lds, lds + KC * LST);
}

// output fc: A = ws+OO [384][512], W = Wo [512][512]. grid 12 x 16 = 192 blocks
__global__ __launch_bounds__(256) void k_out(
    const float* __restrict__ Wo, const float* __restrict__ bo,
    const float* __restrict__ ws, float* __restrict__ out)
{
    __shared__ float lds[2 * KC * LST];
    int bi = blockIdx.x;
    int d0 = (bi & 15) * 32;
    int r0 = (bi >> 4) * 32;
    gemm_tile(ws + OO, Wo, bo, out, 512, r0, d0, lds, lds + KC * LST);
}

__global__ __launch_bounds__(256) void k_tabs(
    const float* __restrict__ entity, const float* __restrict__ Wa,
    float* __restrict__ ws)
{
    int w    = blockIdx.x * 4 + (threadIdx.x >> 6);  // 0..2303 (12 tabs x 192)
    int lane = threadIdx.x & 63;
    int tab  = w / SS;
    int idx  = w % SS;
    const float* q = ws + QO;
    const float* k = ws + KO;
    const float* e = ws + EO;
    const float* src; const float* wt;
    if (tab < 4) {
        int b = tab >> 1, h = tab & 1;
        src = (h ? e : q) + (size_t)(idx * 2 + b) * 256;  wt = Wa;
    } else if (tab < 8) {
        int p = tab - 4; int b = p >> 1, h = p & 1;
        src = (h ? e : k) + (size_t)(idx * 2 + b) * 256;  wt = Wa + 256;
    } else {
        int m = tab - 8;
        src = entity + (size_t)(idx * 2 + (m >> 1)) * 512 + (m & 1) * 256;  wt = Wa + 512;
    }
    float p = 0.f;
    #pragma unroll
    for (int i = 0; i < 4; i++) p += src[lane + 64 * i] * wt[lane + 64 * i];
    #pragma unroll
    for (int off = 32; off >= 1; off >>= 1) p += __shfl_xor(p, off, 64);
    if (lane == 0) ws[TO + tab * SS + idx] = p;
}

// attention: 4 t per block (one per wave), shared PV pass. grid 192 blocks.
__global__ __launch_bounds__(256) void k_attn(
    const float* __restrict__ ba_p, float* __restrict__ ws)
{
    __shared__ float sp[4][SS];
    int bi = blockIdx.x;       // 0..191
    int bh = bi & 3;
    int tg = bi >> 2;          // 0..47
    int b = bh >> 1, h = bh & 1;
    const float* T = ws + TO;
    float ba = ba_p[0];
    int tid  = threadIdx.x;
    int wave = tid >> 6, lane = tid & 63;
    int t = tg * 4 + wave;
    int i_idx = bh * 48 + (t >> 2);
    int tmod  = t & 3;

    // wave-private softmax over 192 scores (3 per lane), no barriers
    float sc[3];
    float mx = -1e30f;
    #pragma unroll
    for (int i = 0; i < 3; i++) {
        int s_ = lane + 64 * i;
        int m  = s_ & 3;
        int j  = tmod * 48 + (s_ >> 2);
        float x = T[m * SS + i_idx] + T[(4 + tmod) * SS + s_]
                + T[(8 + m) * SS + i_idx] - T[(8 + m) * SS + j] + ba;
        x = (x >= 0.f) ? x : 0.01f * x;    // leaky_relu
        sc[i] = x;
        mx = fmaxf(mx, x);
    }
    #pragma unroll
    for (int o = 32; o >= 1; o >>= 1) mx = fmaxf(mx, __shfl_xor(mx, o, 64));
    float sum = 0.f;
    #pragma unroll
    for (int i = 0; i < 3; i++) { sc[i] = __expf(sc[i] - mx); sum += sc[i]; }
    #pragma unroll
    for (int o = 32; o >= 1; o >>= 1) sum += __shfl_xor(sum, o, 64);
    float inv = 1.f / sum;
    #pragma unroll
    for (int i = 0; i < 3; i++) sp[wave][lane + 64 * i] = sc[i] * inv;
    __syncthreads();

    // PV: thread d = tid; each V element serves all 4 t's
    const float* base = (h ? ws + EO : ws + VO) + b * 256 + tid;
    float a0 = 0.f, a1 = 0.f, a2 = 0.f, a3 = 0.f;
    #pragma unroll 4
    for (int s = 0; s < SS; s++) {
        float v = base[(size_t)s * 512];
        a0 += sp[0][s] * v; a1 += sp[1][s] * v;
        a2 += sp[2][s] * v; a3 += sp[3][s] * v;
    }
    // out row = 2t+b, col = h*256+d  (contiguous A for k_out)
    size_t colbase = (size_t)h * 256 + tid;
    int t0 = tg * 4;
    ws[OO + (size_t)((t0 + 0) * 2 + b) * 512 + colbase] = a0;
    ws[OO + (size_t)((t0 + 1) * 2 + b) * 512 + colbase] = a1;
    ws[OO + (size_t)((t0 + 2) * 2 + b) * 512 + colbase] = a2;
    ws[OO + (size_t)((t0 + 3) * 2 + b) * 512 + colbase] = a3;
}

extern "C" void kernel_launch(void* const* d_in, const int* in_sizes, int n_in,
                              void* d_out, int out_size, void* d_ws, size_t ws_size,
                              hipStream_t stream) {
    const float* query  = (const float*)d_in[0];
    const float* entity = (const float*)d_in[1];
    // d_in[2] ex_entity, d_in[3] ex_relation: dead
    const float* Wq = (const float*)d_in[4];  const float* bq = (const float*)d_in[5];
    const float* Wk = (const float*)d_in[6];  const float* bk = (const float*)d_in[7];
    const float* Wv = (const float*)d_in[8];  const float* bv = (const float*)d_in[9];
    const float* We = (const float*)d_in[10]; const float* be = (const float*)d_in[11];
    // d_in[12..15] dead
    const float* Wa = (const float*)d_in[16]; const float* ba = (const float*)d_in[17];
    const float* Wo = (const float*)d_in[18]; const float* bo = (const float*)d_in[19];
    float* ws  = (float*)d_ws;
    float* out = (float*)d_out;

    hipLaunchKernelGGL(k_proj, dim3(384), dim3(256), 0, stream,
                       query, entity, Wq, bq, Wk, bk, Wv, bv, We, be, ws);
    hipLaunchKernelGGL(k_tabs, dim3(576), dim3(256), 0, stream, entity, Wa, ws);
    hipLaunchKernelGGL(k_attn, dim3(192), dim3(256), 0, stream, ba, ws);
    hipLaunchKernelGGL(k_out,  dim3(192), dim3(256), 0, stream, Wo, bo, ws, out);
}